// Round 15
// baseline (92.409 us; speedup 1.0000x reference)
//
#include <hip/hip_runtime.h>
#include <hip/hip_bf16.h>
#include <math.h>

// Problem constants (B, N, D) = (256, 128, 128)
#define B_    256
#define N_    128
#define MAXP  30
#define OTHER_ 35
#define CIN1  131
#define NIDX  381

#define KPAD1 160
#define KPAD2 256
#define KPAD3 128
#define S_IDX (B_ * NIDX)          // 97536
#define S_P1  (15 * 4 * 4 * 512)   // 122880  (gks * NWO4 * SUB4 * 512)
#define S_P2  (24 * 4 * 2 * 512)   // 98304
#define S_P3  (12 * 4 * 1 * 512)   // 24576
#define PREP_TOTAL (S_IDX + S_P1 + S_P2 + S_P3)
#define PREP_BLOCKS ((PREP_TOTAL + 511) / 512)
#define EMBED_BLOCKS (B_ * 4)

typedef short short8 __attribute__((ext_vector_type(8)));
typedef float f32x4 __attribute__((ext_vector_type(4)));

// RNE split of f32 into hi/lo bf16 via bit math (prep only)
__device__ inline void split1(float v, short& h, short& l) {
  unsigned u = __float_as_uint(v);
  unsigned hb = (u + 0x7fffu + ((u >> 16) & 1u)) >> 16;
  float fh = __uint_as_float(hb << 16);
  float r = v - fh;
  unsigned u2 = __float_as_uint(r);
  unsigned lb = (u2 + 0x7fffu + ((u2 >> 16) & 1u)) >> 16;
  h = (short)hb;
  l = (short)lb;
}

// RNE split via HW cvt — hot path
__device__ inline void split2(float v, short& h, short& l) {
  __hip_bfloat16 hb = __float2bfloat16(v);
  float fh = __bfloat162float(hb);
  __hip_bfloat16 lb = __float2bfloat16(v - fh);
  __builtin_memcpy(&h, &hb, 2);
  __builtin_memcpy(&l, &lb, 2);
}

// ---------------------------------------------------------------------------
// Weight pack: l -> [gks][g][su][lane][e]; g in [0,NWO). Value w[oc][ch][kk],
// oc=(g*SUB+su)*16+(lane&15), ctot=gks*32+((lane>>4)&3)*8+e,
// kk=ctot/KPAD, ch=ctot%KPAD (0 if ch>=KREAL).
// ---------------------------------------------------------------------------
template <int KREAL, int KPAD, int SUB, int NWO>
__device__ inline void packw(int l, const float* __restrict__ w,
                             short* __restrict__ oh, short* __restrict__ ol) {
  const int e = l & 7;
  const int lane = (l >> 3) & 63;
  const int x = l >> 9;
  const int su = x % SUB;
  const int y = x / SUB;
  const int g = y % NWO;
  const int gks = y / NWO;
  const int oc = (g * SUB + su) * 16 + (lane & 15);
  const int ctot = gks * 32 + ((lane >> 4) & 3) * 8 + e;
  const int kk = ctot / KPAD;
  const int ch = ctot - kk * KPAD;
  const float v = (ch < KREAL) ? w[(oc * KREAL + ch) * 3 + kk] : 0.f;
  short h, lo;
  split1(v, h, lo);
  oh[l] = h;
  ol[l] = lo;
}

// ---------------------------------------------------------------------------
// Merged prep + embed (identical to r14).
// ---------------------------------------------------------------------------
__global__ __launch_bounds__(512) void prep_embed_kernel(
    const float* __restrict__ feature,
    const float* __restrict__ col_embed,   // (200,32)
    const float* __restrict__ op_embed,    // (20,32)
    short* __restrict__ collateH, short* __restrict__ collateL,
    const void* __restrict__ rawIdx, int* __restrict__ idx32,
    const float* __restrict__ w1, short* __restrict__ w1h, short* __restrict__ w1l,
    const float* __restrict__ w2, short* __restrict__ w2h, short* __restrict__ w2l,
    const float* __restrict__ w3, short* __restrict__ w3h, short* __restrict__ w3l) {
  const int bx = blockIdx.x;
  const int tid = threadIdx.x;

  if (bx >= EMBED_BLOCKS) {
    const int gid = (bx - EMBED_BLOCKS) * 512 + tid;
    if (gid < S_IDX) {
      // int64 LE view is (v,0,v,0,...) with v in [0,128)
      const int* r32 = (const int*)rawIdx;
      const int lane = tid & 63;
      const int lo = r32[2 * lane];
      const int hi = r32[2 * lane + 1];
      const bool ok = (hi == 0 && lo >= 0 && lo < N_);
      const bool is64 = __all(ok);
      idx32[gid] = is64 ? (int)((const long long*)rawIdx)[gid] : ((const int*)rawIdx)[gid];
    } else if (gid < S_IDX + S_P1) {
      packw<131, KPAD1, 4, 4>(gid - S_IDX, w1, w1h, w1l);
    } else if (gid < S_IDX + S_P1 + S_P2) {
      packw<256, KPAD2, 2, 4>(gid - (S_IDX + S_P1), w2, w2h, w2l);
    } else if (gid < PREP_TOTAL) {
      packw<128, KPAD3, 1, 4>(gid - (S_IDX + S_P1 + S_P2), w3, w3h, w3l);
    }
    return;
  }

  __shared__ float feat[128 * 33];
  __shared__ float ce[200 * 32];
  __shared__ float oe[20 * 32];
  const int b = bx >> 2;
  const int n0 = (bx & 3) * 32;
  const float* fb = feature + (size_t)b * 16384;

  {
    const float4* s = (const float4*)col_embed;
    float4* d = (float4*)ce;
#pragma unroll
    for (int it = 0; it < 4; ++it) {
      const int t = it * 512 + tid;
      if (t < 1600) d[t] = s[t];
    }
    if (tid < 160) ((float4*)oe)[tid] = ((const float4*)op_embed)[tid];
  }
  {
    const int d = tid >> 2;
    const int c8 = (tid & 3) * 8;
    const float4 v0 = *reinterpret_cast<const float4*>(&fb[d * 128 + n0 + c8]);
    const float4 v1 = *reinterpret_cast<const float4*>(&fb[d * 128 + n0 + c8 + 4]);
    float* p = &feat[d * 33 + c8];
    p[0] = v0.x; p[1] = v0.y; p[2] = v0.z; p[3] = v0.w;
    p[4] = v1.x; p[5] = v1.y; p[6] = v1.z; p[7] = v1.w;
  }
  __syncthreads();

  const int wv = tid >> 6;
  const int lane = tid & 63;
  const int cl = lane & 31;

#pragma unroll
  for (int ni = 0; ni < 4; ++ni) {
    const int nl = wv * 4 + ni;
    const int n = n0 + nl;
    int civ = 0, oiv = 0;
    if (lane < MAXP) civ = (int)feat[(OTHER_ + lane) * 33 + nl];
    if (lane >= 32 && lane < 32 + MAXP) oiv = (int)feat[(OTHER_ + MAXP + (lane - 32)) * 33 + nl];
    const int L = (int)feat[95 * 33 + nl];

    float acc = 0.f;
    for (int i = 0; i < L; ++i) {
      const int cv = __shfl(civ, i);
      const int ov = __shfl(oiv, 32 + i);
      acc += (lane < 32) ? ce[cv * 32 + cl] : oe[ov * 32 + cl];
    }

    short* outH = collateH + ((size_t)b * 128 + n) * KPAD1;
    short* outL = collateL + ((size_t)b * 128 + n) * KPAD1;
    short h, l;
    split2(acc, h, l);
    outH[35 + lane] = h; outL[35 + lane] = l;
    if (lane < 35) {
      split2(feat[lane * 33 + nl], h, l);
      outH[lane] = h; outL[lane] = l;
    }
    if (lane < 32) {
      split2(feat[(96 + lane) * 33 + nl], h, l);
      outH[99 + lane] = h; outL[99 + lane] = l;
    }
    if (lane < 29) { outH[131 + lane] = 0; outL[131 + lane] = 0; }
  }
}

// ---------------------------------------------------------------------------
// FUSED v4: r14 structure + conflict-free LDS stride (266 shorts = 133
// dwords, 133 mod 32 = 5 coprime -> random gather rows hit all 32 banks)
// + weight DOUBLE-BUFFER in each gks loop (next gks's VMEM loads issued
// before current gks's MFMAs; parity constant-folds after full unroll).
// 16 waves (wj 0..3 x wo 0..3), wave = 32 j (JT=2) x oc-quarter.
// ---------------------------------------------------------------------------
__global__ __launch_bounds__(1024, 1) void fused_kernel(
    const short* __restrict__ XH, const short* __restrict__ XL,
    const int* __restrict__ idx,
    const short* __restrict__ w1h, const short* __restrict__ w1l,
    const short* __restrict__ w2h, const short* __restrict__ w2l,
    const short* __restrict__ w3h, const short* __restrict__ w3l,
    const float* __restrict__ b1, const float* __restrict__ b2,
    const float* __restrict__ b3,
    const float* __restrict__ fw1, const float* __restrict__ fb1,
    const float* __restrict__ fw2, const float* __restrict__ fb2,
    float* __restrict__ out) {
  constexpr int CINP = 266;   // shorts per row = 133 dwords (odd mod 32)

  __shared__ short sH[128 * CINP];   // 68.1 KB
  __shared__ short sL[128 * CINP];   // 68.1 KB
  __shared__ int nb_s[NIDX];
  __shared__ double red[32];
  __shared__ float bc[2];
  __shared__ float poolw[16][16];

  const int b = blockIdx.x;
  const int tid = threadIdx.x;
  const int lane = tid & 63;
  const int w = tid >> 6;       // 0..15
  const int wj = w >> 2;        // 0..3
  const int wo = w & 3;         // 0..3
  const int col = lane & 15;
  const int grp = (lane >> 4) & 3;
  const int jbase = wj * 32;

  const short8* __restrict__ wp1h = (const short8*)w1h;
  const short8* __restrict__ wp1l = (const short8*)w1l;
  const short8* __restrict__ wp2h = (const short8*)w2h;
  const short8* __restrict__ wp2l = (const short8*)w2l;
  const short8* __restrict__ wp3h = (const short8*)w3h;
  const short8* __restrict__ wp3l = (const short8*)w3l;

  auto blockStats = [&](double ss, double sq, double cnt) {
#pragma unroll
    for (int o = 32; o > 0; o >>= 1) {
      ss += __shfl_down(ss, o, 64);
      sq += __shfl_down(sq, o, 64);
    }
    if (lane == 0) { red[w * 2] = ss; red[w * 2 + 1] = sq; }
    __syncthreads();
    if (tid == 0) {
      double S = 0.0, Q = 0.0;
#pragma unroll
      for (int i = 0; i < 16; ++i) { S += red[i * 2]; Q += red[i * 2 + 1]; }
      const double m = S / cnt;
      double var = (Q - S * S / cnt) / (cnt - 1.0);
      if (var < 0.0) var = 0.0;
      bc[0] = (float)m;
      bc[1] = (float)(1.0 / (sqrt(var) + 1e-5));
    }
    __syncthreads();
  };

  // ---------------- conv1: stage full 160 ch (PURE copy) ----------------
  {
    const short* __restrict__ XHb = XH + (size_t)b * (128 * KPAD1);
    const short* __restrict__ XLb = XL + (size_t)b * (128 * KPAD1);
#pragma unroll
    for (int it = 0; it < 3; ++it) {
      const int t = it * 1024 + tid;
      if (t < 128 * 20) {                 // PKs = 160/8 = 20
        const int n = t / 20;
        const int c0 = (t - n * 20) * 8;
        *reinterpret_cast<short8*>(&sH[n * CINP + c0]) =
            *reinterpret_cast<const short8*>(&XHb[n * KPAD1 + c0]);
        *reinterpret_cast<short8*>(&sL[n * CINP + c0]) =
            *reinterpret_cast<const short8*>(&XLb[n * KPAD1 + c0]);
      }
    }
  }
  if (tid < NIDX) nb_s[tid] = idx[b * NIDX + tid];
  __syncthreads();

  int nbr[2][3];
#pragma unroll
  for (int jt = 0; jt < 2; ++jt) {
    const int jA = jbase + jt * 16 + col;
#pragma unroll
    for (int kk = 0; kk < 3; ++kk)
      nbr[jt][kk] = (jA > 0) ? nb_s[(jA - 1) * 3 + kk] : 0;
  }

  // ---------------- conv1 compute: COUT 256, SUB=4, weight dbuf ----------
  f32x4 a1[2][4];
#pragma unroll
  for (int jt = 0; jt < 2; ++jt)
#pragma unroll
    for (int su = 0; su < 4; ++su) {
      a1[jt][su][0] = 0.f; a1[jt][su][1] = 0.f;
      a1[jt][su][2] = 0.f; a1[jt][su][3] = 0.f;
    }

  {
    short8 bh[2][4], bl[2][4];
    auto LOADW = [&](int gks, int p) {
#pragma unroll
      for (int su = 0; su < 4; ++su) {
        const int wi = ((gks * 4 + wo) * 4 + su) * 64 + lane;
        bh[p][su] = wp1h[wi];
        bl[p][su] = wp1l[wi];
      }
    };
    LOADW(0, 0);
#pragma unroll
    for (int it = 0; it < 15; ++it) {
      if (it + 1 < 15) LOADW(it + 1, (it + 1) & 1);
      const int kk = it / 5, ks = it - kk * 5;
      short8 ah[2], al[2];
#pragma unroll
      for (int jt = 0; jt < 2; ++jt) {
        const int ei = nbr[jt][kk] * CINP + ks * 32 + grp * 8;
        ah[jt] = *reinterpret_cast<const short8*>(&sH[ei]);
        al[jt] = *reinterpret_cast<const short8*>(&sL[ei]);
      }
      const int p = it & 1;
#pragma unroll
      for (int jt = 0; jt < 2; ++jt)
#pragma unroll
        for (int su = 0; su < 4; ++su) {
          a1[jt][su] = __builtin_amdgcn_mfma_f32_16x16x32_bf16(ah[jt], bh[p][su], a1[jt][su], 0, 0, 0);
          a1[jt][su] = __builtin_amdgcn_mfma_f32_16x16x32_bf16(al[jt], bh[p][su], a1[jt][su], 0, 0, 0);
          a1[jt][su] = __builtin_amdgcn_mfma_f32_16x16x32_bf16(ah[jt], bl[p][su], a1[jt][su], 0, 0, 0);
        }
    }
  }

  // ---- epilogue1: bias, zero col j=0, stats ----
  {
    double ss = 0.0, sq = 0.0;
#pragma unroll
    for (int su = 0; su < 4; ++su) {
      const float bv = b1[(wo * 4 + su) * 16 + col];
#pragma unroll
      for (int jt = 0; jt < 2; ++jt)
#pragma unroll
        for (int r = 0; r < 4; ++r) {
          const int j = jbase + jt * 16 + grp * 4 + r;
          const float val = (j > 0) ? a1[jt][su][r] + bv : 0.f;
          a1[jt][su][r] = val;
          ss += (double)val;
          sq += (double)val * (double)val;
        }
    }
    blockStats(ss, sq, 256.0 * 128.0);
  }
  const float mean1 = bc[0], inv1 = bc[1];

  // ---------------- conv2 stage: all 256 ch from registers ----------------
#pragma unroll
  for (int su = 0; su < 4; ++su) {
    const int c = (wo * 4 + su) * 16 + col;
#pragma unroll
    for (int jt = 0; jt < 2; ++jt)
#pragma unroll
      for (int r = 0; r < 4; ++r) {
        const int j = jbase + jt * 16 + grp * 4 + r;
        float v = (a1[jt][su][r] - mean1) * inv1;
        v = fmaxf(v, 0.01f * v);
        short h, l;
        split2(v, h, l);
        sH[j * CINP + c] = h;
        sL[j * CINP + c] = l;
      }
  }
  __syncthreads();

  // ---------------- conv2 compute: COUT 128, SUB=2, weight dbuf ----------
  f32x4 a2[2][2];
#pragma unroll
  for (int jt = 0; jt < 2; ++jt)
#pragma unroll
    for (int su = 0; su < 2; ++su) {
      a2[jt][su][0] = 0.f; a2[jt][su][1] = 0.f;
      a2[jt][su][2] = 0.f; a2[jt][su][3] = 0.f;
    }

  {
    short8 bh[2][2], bl[2][2];
    auto LOADW = [&](int gks, int p) {
#pragma unroll
      for (int su = 0; su < 2; ++su) {
        const int wi = ((gks * 4 + wo) * 2 + su) * 64 + lane;
        bh[p][su] = wp2h[wi];
        bl[p][su] = wp2l[wi];
      }
    };
    LOADW(0, 0);
#pragma unroll
    for (int it = 0; it < 24; ++it) {
      if (it + 1 < 24) LOADW(it + 1, (it + 1) & 1);
      const int kk = it / 8, ks = it - kk * 8;
      short8 ah[2], al[2];
#pragma unroll
      for (int jt = 0; jt < 2; ++jt) {
        const int ei = nbr[jt][kk] * CINP + ks * 32 + grp * 8;
        ah[jt] = *reinterpret_cast<const short8*>(&sH[ei]);
        al[jt] = *reinterpret_cast<const short8*>(&sL[ei]);
      }
      const int p = it & 1;
#pragma unroll
      for (int jt = 0; jt < 2; ++jt)
#pragma unroll
        for (int su = 0; su < 2; ++su) {
          a2[jt][su] = __builtin_amdgcn_mfma_f32_16x16x32_bf16(ah[jt], bh[p][su], a2[jt][su], 0, 0, 0);
          a2[jt][su] = __builtin_amdgcn_mfma_f32_16x16x32_bf16(al[jt], bh[p][su], a2[jt][su], 0, 0, 0);
          a2[jt][su] = __builtin_amdgcn_mfma_f32_16x16x32_bf16(ah[jt], bl[p][su], a2[jt][su], 0, 0, 0);
        }
    }
  }

  // ---- epilogue2 ----
  {
    double ss = 0.0, sq = 0.0;
#pragma unroll
    for (int su = 0; su < 2; ++su) {
      const float bv = b2[(wo * 2 + su) * 16 + col];
#pragma unroll
      for (int jt = 0; jt < 2; ++jt)
#pragma unroll
        for (int r = 0; r < 4; ++r) {
          const int j = jbase + jt * 16 + grp * 4 + r;
          const float val = (j > 0) ? a2[jt][su][r] + bv : 0.f;
          a2[jt][su][r] = val;
          ss += (double)val;
          sq += (double)val * (double)val;
        }
    }
    blockStats(ss, sq, 128.0 * 128.0);
  }
  const float mean2 = bc[0], inv2 = bc[1];

  // ---------------- conv3 stage: all 128 ch ----------------
#pragma unroll
  for (int su = 0; su < 2; ++su) {
    const int c = (wo * 2 + su) * 16 + col;
#pragma unroll
    for (int jt = 0; jt < 2; ++jt)
#pragma unroll
      for (int r = 0; r < 4; ++r) {
        const int j = jbase + jt * 16 + grp * 4 + r;
        float v = (a2[jt][su][r] - mean2) * inv2;
        v = fmaxf(v, 0.01f * v);
        short h, l;
        split2(v, h, l);
        sH[j * CINP + c] = h;
        sL[j * CINP + c] = l;
      }
  }
  __syncthreads();

  // ---------------- conv3 compute: COUT 64, SUB=1, weight dbuf ----------
  f32x4 a3[2];
#pragma unroll
  for (int jt = 0; jt < 2; ++jt) {
    a3[jt][0] = 0.f; a3[jt][1] = 0.f; a3[jt][2] = 0.f; a3[jt][3] = 0.f;
  }

  {
    short8 bh[2], bl[2];
    auto LOADW = [&](int gks, int p) {
      const int wi = (gks * 4 + wo) * 64 + lane;
      bh[p] = wp3h[wi];
      bl[p] = wp3l[wi];
    };
    LOADW(0, 0);
#pragma unroll
    for (int it = 0; it < 12; ++it) {
      if (it + 1 < 12) LOADW(it + 1, (it + 1) & 1);
      const int kk = it / 4, ks = it - kk * 4;
      short8 ah[2], al[2];
#pragma unroll
      for (int jt = 0; jt < 2; ++jt) {
        const int ei = nbr[jt][kk] * CINP + ks * 32 + grp * 8;
        ah[jt] = *reinterpret_cast<const short8*>(&sH[ei]);
        al[jt] = *reinterpret_cast<const short8*>(&sL[ei]);
      }
      const int p = it & 1;
#pragma unroll
      for (int jt = 0; jt < 2; ++jt) {
        a3[jt] = __builtin_amdgcn_mfma_f32_16x16x32_bf16(ah[jt], bh[p], a3[jt], 0, 0, 0);
        a3[jt] = __builtin_amdgcn_mfma_f32_16x16x32_bf16(al[jt], bh[p], a3[jt], 0, 0, 0);
        a3[jt] = __builtin_amdgcn_mfma_f32_16x16x32_bf16(ah[jt], bl[p], a3[jt], 0, 0, 0);
      }
    }
  }

  // ---- epilogue3 + stats ----
  {
    double ss = 0.0, sq = 0.0;
    const float bv = b3[wo * 16 + col];
#pragma unroll
    for (int jt = 0; jt < 2; ++jt)
#pragma unroll
      for (int r = 0; r < 4; ++r) {
        const int j = jbase + jt * 16 + grp * 4 + r;
        const float val = (j > 0) ? a3[jt][r] + bv : 0.f;
        a3[jt][r] = val;
        ss += (double)val;
        sq += (double)val * (double)val;
      }
    blockStats(ss, sq, 64.0 * 128.0);
  }
  const float mean3 = bc[0], inv3 = bc[1];

  // ---- maxpool over this wave's j-range, then cross-wj in LDS ----
  {
    float pm = -3.4e38f;
#pragma unroll
    for (int jt = 0; jt < 2; ++jt)
#pragma unroll
      for (int r = 0; r < 4; ++r)
        pm = fmaxf(pm, (a3[jt][r] - mean3) * inv3);
    pm = fmaxf(pm, __shfl_xor(pm, 16, 64));
    pm = fmaxf(pm, __shfl_xor(pm, 32, 64));
    if (lane < 16) poolw[w][col] = pm;
  }
  __syncthreads();

  // ---- 2-layer MLP (wave 0) ----
  if (w == 0) {
    float hval = 0.f;
    if (lane < 32) {
      float a = fb1[lane];
#pragma unroll 8
      for (int c = 0; c < 64; ++c) {
        const int oq = c >> 4, oc16 = c & 15;
        float p = poolw[oq][oc16];
#pragma unroll
        for (int jw = 1; jw < 4; ++jw) p = fmaxf(p, poolw[jw * 4 + oq][oc16]);
        a = fmaf(p, fw1[lane * 64 + c], a);
      }
      hval = fmaxf(a, 0.f) * fw2[lane];
    }
#pragma unroll
    for (int o = 32; o > 0; o >>= 1) hval += __shfl_down(hval, o, 64);
    if (lane == 0) out[b] = hval + fb2[0];
  }
}

// ---------------------------------------------------------------------------
extern "C" void kernel_launch(void* const* d_in, const int* in_sizes, int n_in,
                              void* d_out, int out_size, void* d_ws, size_t ws_size,
                              hipStream_t stream) {
  const float* feature   = (const float*)d_in[0];
  const void*  indexes   = d_in[1];
  const float* col_embed = (const float*)d_in[2];
  const float* op_embed  = (const float*)d_in[3];
  const float* w1  = (const float*)d_in[4];
  const float* b1  = (const float*)d_in[5];
  const float* w2  = (const float*)d_in[6];
  const float* b2  = (const float*)d_in[7];
  const float* w3  = (const float*)d_in[8];
  const float* b3  = (const float*)d_in[9];
  const float* fw1 = (const float*)d_in[10];
  const float* fb1 = (const float*)d_in[11];
  const float* fw2 = (const float*)d_in[12];
  const float* fb2 = (const float*)d_in[13];
  float* out = (float*)d_out;

  char* ws = (char*)d_ws;
  size_t off = 0;
  auto carve = [&](size_t bytes) -> char* {
    off = (off + 255) & ~(size_t)255;
    char* p = ws + off;
    off += bytes;
    return p;
  };
  int*   idx32    = (int*)carve((size_t)S_IDX * sizeof(int));
  short* w1h      = (short*)carve((size_t)S_P1 * sizeof(short));
  short* w1l      = (short*)carve((size_t)S_P1 * sizeof(short));
  short* w2h      = (short*)carve((size_t)S_P2 * sizeof(short));
  short* w2l      = (short*)carve((size_t)S_P2 * sizeof(short));
  short* w3h      = (short*)carve((size_t)S_P3 * sizeof(short));
  short* w3l      = (short*)carve((size_t)S_P3 * sizeof(short));
  short* collateH = (short*)carve((size_t)B_ * 128 * KPAD1 * sizeof(short));
  short* collateL = (short*)carve((size_t)B_ * 128 * KPAD1 * sizeof(short));
  (void)ws_size; (void)in_sizes; (void)n_in; (void)out_size;

  hipLaunchKernelGGL(prep_embed_kernel, dim3(EMBED_BLOCKS + PREP_BLOCKS), dim3(512), 0, stream,
                     feature, col_embed, op_embed, collateH, collateL,
                     indexes, idx32, w1, w1h, w1l, w2, w2h, w2l, w3, w3h, w3l);
  hipLaunchKernelGGL(fused_kernel, dim3(B_), dim3(1024), 0, stream,
                     collateH, collateL, idx32,
                     w1h, w1l, w2h, w2l, w3h, w3l,
                     b1, b2, b3, fw1, fb1, fw2, fb2, out);
}

// Round 16
// 90.690 us; speedup vs baseline: 1.0190x; 1.0190x over previous
//
#include <hip/hip_runtime.h>
#include <hip/hip_bf16.h>
#include <math.h>

// Problem constants (B, N, D) = (256, 128, 128)
#define B_    256
#define N_    128
#define MAXP  30
#define OTHER_ 35
#define CIN1  131
#define NIDX  381

#define KPAD1 160
#define KPAD2 256
#define KPAD3 128
#define S_IDX (B_ * NIDX)          // 97536
#define S_P1  (15 * 4 * 4 * 512)   // 122880  (gks * NWO4 * SUB4 * 512)
#define S_P2  (24 * 4 * 2 * 512)   // 98304
#define S_P3  (12 * 4 * 1 * 512)   // 24576
#define PREP_TOTAL (S_IDX + S_P1 + S_P2 + S_P3)
#define PREP_BLOCKS ((PREP_TOTAL + 511) / 512)
#define EMBED_BLOCKS (B_ * 4)

typedef short short8 __attribute__((ext_vector_type(8)));
typedef float f32x4 __attribute__((ext_vector_type(4)));

// swizzled LDS index: 16B-granule XOR by row (G4 recipe: byte ^= (row&7)<<4)
#define SWZ(row, idx) ((idx) ^ (((row) & 7) << 3))

// RNE split of f32 into hi/lo bf16 via bit math (prep only)
__device__ inline void split1(float v, short& h, short& l) {
  unsigned u = __float_as_uint(v);
  unsigned hb = (u + 0x7fffu + ((u >> 16) & 1u)) >> 16;
  float fh = __uint_as_float(hb << 16);
  float r = v - fh;
  unsigned u2 = __float_as_uint(r);
  unsigned lb = (u2 + 0x7fffu + ((u2 >> 16) & 1u)) >> 16;
  h = (short)hb;
  l = (short)lb;
}

// RNE split via HW cvt — hot path
__device__ inline void split2(float v, short& h, short& l) {
  __hip_bfloat16 hb = __float2bfloat16(v);
  float fh = __bfloat162float(hb);
  __hip_bfloat16 lb = __float2bfloat16(v - fh);
  __builtin_memcpy(&h, &hb, 2);
  __builtin_memcpy(&l, &lb, 2);
}

// ---------------------------------------------------------------------------
// Weight pack: l -> [gks][g][su][lane][e]; g in [0,NWO). Value w[oc][ch][kk],
// oc=(g*SUB+su)*16+(lane&15), ctot=gks*32+((lane>>4)&3)*8+e,
// kk=ctot/KPAD, ch=ctot%KPAD (0 if ch>=KREAL).
// ---------------------------------------------------------------------------
template <int KREAL, int KPAD, int SUB, int NWO>
__device__ inline void packw(int l, const float* __restrict__ w,
                             short* __restrict__ oh, short* __restrict__ ol) {
  const int e = l & 7;
  const int lane = (l >> 3) & 63;
  const int x = l >> 9;
  const int su = x % SUB;
  const int y = x / SUB;
  const int g = y % NWO;
  const int gks = y / NWO;
  const int oc = (g * SUB + su) * 16 + (lane & 15);
  const int ctot = gks * 32 + ((lane >> 4) & 3) * 8 + e;
  const int kk = ctot / KPAD;
  const int ch = ctot - kk * KPAD;
  const float v = (ch < KREAL) ? w[(oc * KREAL + ch) * 3 + kk] : 0.f;
  short h, lo;
  split1(v, h, lo);
  oh[l] = h;
  ol[l] = lo;
}

// ---------------------------------------------------------------------------
// Merged prep + embed (identical to r14).
// ---------------------------------------------------------------------------
__global__ __launch_bounds__(512) void prep_embed_kernel(
    const float* __restrict__ feature,
    const float* __restrict__ col_embed,   // (200,32)
    const float* __restrict__ op_embed,    // (20,32)
    short* __restrict__ collateH, short* __restrict__ collateL,
    const void* __restrict__ rawIdx, int* __restrict__ idx32,
    const float* __restrict__ w1, short* __restrict__ w1h, short* __restrict__ w1l,
    const float* __restrict__ w2, short* __restrict__ w2h, short* __restrict__ w2l,
    const float* __restrict__ w3, short* __restrict__ w3h, short* __restrict__ w3l) {
  const int bx = blockIdx.x;
  const int tid = threadIdx.x;

  if (bx >= EMBED_BLOCKS) {
    const int gid = (bx - EMBED_BLOCKS) * 512 + tid;
    if (gid < S_IDX) {
      // int64 LE view is (v,0,v,0,...) with v in [0,128)
      const int* r32 = (const int*)rawIdx;
      const int lane = tid & 63;
      const int lo = r32[2 * lane];
      const int hi = r32[2 * lane + 1];
      const bool ok = (hi == 0 && lo >= 0 && lo < N_);
      const bool is64 = __all(ok);
      idx32[gid] = is64 ? (int)((const long long*)rawIdx)[gid] : ((const int*)rawIdx)[gid];
    } else if (gid < S_IDX + S_P1) {
      packw<131, KPAD1, 4, 4>(gid - S_IDX, w1, w1h, w1l);
    } else if (gid < S_IDX + S_P1 + S_P2) {
      packw<256, KPAD2, 2, 4>(gid - (S_IDX + S_P1), w2, w2h, w2l);
    } else if (gid < PREP_TOTAL) {
      packw<128, KPAD3, 1, 4>(gid - (S_IDX + S_P1 + S_P2), w3, w3h, w3l);
    }
    return;
  }

  __shared__ float feat[128 * 33];
  __shared__ float ce[200 * 32];
  __shared__ float oe[20 * 32];
  const int b = bx >> 2;
  const int n0 = (bx & 3) * 32;
  const float* fb = feature + (size_t)b * 16384;

  {
    const float4* s = (const float4*)col_embed;
    float4* d = (float4*)ce;
#pragma unroll
    for (int it = 0; it < 4; ++it) {
      const int t = it * 512 + tid;
      if (t < 1600) d[t] = s[t];
    }
    if (tid < 160) ((float4*)oe)[tid] = ((const float4*)op_embed)[tid];
  }
  {
    const int d = tid >> 2;
    const int c8 = (tid & 3) * 8;
    const float4 v0 = *reinterpret_cast<const float4*>(&fb[d * 128 + n0 + c8]);
    const float4 v1 = *reinterpret_cast<const float4*>(&fb[d * 128 + n0 + c8 + 4]);
    float* p = &feat[d * 33 + c8];
    p[0] = v0.x; p[1] = v0.y; p[2] = v0.z; p[3] = v0.w;
    p[4] = v1.x; p[5] = v1.y; p[6] = v1.z; p[7] = v1.w;
  }
  __syncthreads();

  const int wv = tid >> 6;
  const int lane = tid & 63;
  const int cl = lane & 31;

#pragma unroll
  for (int ni = 0; ni < 4; ++ni) {
    const int nl = wv * 4 + ni;
    const int n = n0 + nl;
    int civ = 0, oiv = 0;
    if (lane < MAXP) civ = (int)feat[(OTHER_ + lane) * 33 + nl];
    if (lane >= 32 && lane < 32 + MAXP) oiv = (int)feat[(OTHER_ + MAXP + (lane - 32)) * 33 + nl];
    const int L = (int)feat[95 * 33 + nl];

    float acc = 0.f;
    for (int i = 0; i < L; ++i) {
      const int cv = __shfl(civ, i);
      const int ov = __shfl(oiv, 32 + i);
      acc += (lane < 32) ? ce[cv * 32 + cl] : oe[ov * 32 + cl];
    }

    short* outH = collateH + ((size_t)b * 128 + n) * KPAD1;
    short* outL = collateL + ((size_t)b * 128 + n) * KPAD1;
    short h, l;
    split2(acc, h, l);
    outH[35 + lane] = h; outL[35 + lane] = l;
    if (lane < 35) {
      split2(feat[lane * 33 + nl], h, l);
      outH[lane] = h; outL[lane] = l;
    }
    if (lane < 32) {
      split2(feat[(96 + lane) * 33 + nl], h, l);
      outH[99 + lane] = h; outL[99 + lane] = l;
    }
    if (lane < 29) { outH[131 + lane] = 0; outL[131 + lane] = 0; }
  }
}

// ---------------------------------------------------------------------------
// FUSED v5 = r14 structure + XOR-swizzled LDS (CINP 256 shorts = 512 B rows;
// granule idx ^= (row&7)<<3 on write AND read -> 16 random gather rows spread
// bank-quads ~2-way = free). 16 waves (wj 0..3 x wo 0..3), wave = 32 j (JT=2)
// x oc-quarter. Full-layer staging, ~10 barriers. Only global write: out[b].
// ---------------------------------------------------------------------------
__global__ __launch_bounds__(1024, 1) void fused_kernel(
    const short* __restrict__ XH, const short* __restrict__ XL,
    const int* __restrict__ idx,
    const short* __restrict__ w1h, const short* __restrict__ w1l,
    const short* __restrict__ w2h, const short* __restrict__ w2l,
    const short* __restrict__ w3h, const short* __restrict__ w3l,
    const float* __restrict__ b1, const float* __restrict__ b2,
    const float* __restrict__ b3,
    const float* __restrict__ fw1, const float* __restrict__ fb1,
    const float* __restrict__ fw2, const float* __restrict__ fb2,
    float* __restrict__ out) {
  constexpr int CINP = 256;   // shorts per row (512 B, swizzled)

  __shared__ short sH[128 * CINP];   // 64 KB
  __shared__ short sL[128 * CINP];   // 64 KB
  __shared__ int nb_s[NIDX];
  __shared__ double red[32];
  __shared__ float bc[2];
  __shared__ float poolw[16][16];

  const int b = blockIdx.x;
  const int tid = threadIdx.x;
  const int lane = tid & 63;
  const int w = tid >> 6;       // 0..15
  const int wj = w >> 2;        // 0..3
  const int wo = w & 3;         // 0..3
  const int col = lane & 15;
  const int grp = (lane >> 4) & 3;
  const int jbase = wj * 32;

  const short8* __restrict__ wp1h = (const short8*)w1h;
  const short8* __restrict__ wp1l = (const short8*)w1l;
  const short8* __restrict__ wp2h = (const short8*)w2h;
  const short8* __restrict__ wp2l = (const short8*)w2l;
  const short8* __restrict__ wp3h = (const short8*)w3h;
  const short8* __restrict__ wp3l = (const short8*)w3l;

  auto blockStats = [&](double ss, double sq, double cnt) {
#pragma unroll
    for (int o = 32; o > 0; o >>= 1) {
      ss += __shfl_down(ss, o, 64);
      sq += __shfl_down(sq, o, 64);
    }
    if (lane == 0) { red[w * 2] = ss; red[w * 2 + 1] = sq; }
    __syncthreads();
    if (tid == 0) {
      double S = 0.0, Q = 0.0;
#pragma unroll
      for (int i = 0; i < 16; ++i) { S += red[i * 2]; Q += red[i * 2 + 1]; }
      const double m = S / cnt;
      double var = (Q - S * S / cnt) / (cnt - 1.0);
      if (var < 0.0) var = 0.0;
      bc[0] = (float)m;
      bc[1] = (float)(1.0 / (sqrt(var) + 1e-5));
    }
    __syncthreads();
  };

  // ---------------- conv1: stage full 160 ch (PURE copy, swizzled) --------
  {
    const short* __restrict__ XHb = XH + (size_t)b * (128 * KPAD1);
    const short* __restrict__ XLb = XL + (size_t)b * (128 * KPAD1);
#pragma unroll
    for (int it = 0; it < 3; ++it) {
      const int t = it * 1024 + tid;
      if (t < 128 * 20) {                 // PKs = 160/8 = 20
        const int n = t / 20;
        const int c0 = (t - n * 20) * 8;
        const int si = SWZ(n, n * CINP + c0);
        *reinterpret_cast<short8*>(&sH[si]) =
            *reinterpret_cast<const short8*>(&XHb[n * KPAD1 + c0]);
        *reinterpret_cast<short8*>(&sL[si]) =
            *reinterpret_cast<const short8*>(&XLb[n * KPAD1 + c0]);
      }
    }
  }
  if (tid < NIDX) nb_s[tid] = idx[b * NIDX + tid];
  __syncthreads();

  int nbr[2][3];
#pragma unroll
  for (int jt = 0; jt < 2; ++jt) {
    const int jA = jbase + jt * 16 + col;
#pragma unroll
    for (int kk = 0; kk < 3; ++kk)
      nbr[jt][kk] = (jA > 0) ? nb_s[(jA - 1) * 3 + kk] : 0;
  }

  // ---------------- conv1 compute: COUT 256, SUB=4 ----------------
  f32x4 a1[2][4];
#pragma unroll
  for (int jt = 0; jt < 2; ++jt)
#pragma unroll
    for (int su = 0; su < 4; ++su) {
      a1[jt][su][0] = 0.f; a1[jt][su][1] = 0.f;
      a1[jt][su][2] = 0.f; a1[jt][su][3] = 0.f;
    }

#pragma unroll
  for (int kk = 0; kk < 3; ++kk) {
#pragma unroll
    for (int ks = 0; ks < 5; ++ks) {
      const int gks = kk * 5 + ks;
      short8 ah[2], al[2];
#pragma unroll
      for (int jt = 0; jt < 2; ++jt) {
        const int row = nbr[jt][kk];
        const int ei = SWZ(row, row * CINP + ks * 32 + grp * 8);
        ah[jt] = *reinterpret_cast<const short8*>(&sH[ei]);
        al[jt] = *reinterpret_cast<const short8*>(&sL[ei]);
      }
      short8 bh[4], bl[4];
#pragma unroll
      for (int su = 0; su < 4; ++su) {
        const int wi = ((gks * 4 + wo) * 4 + su) * 64 + lane;
        bh[su] = wp1h[wi];
        bl[su] = wp1l[wi];
      }
#pragma unroll
      for (int jt = 0; jt < 2; ++jt)
#pragma unroll
        for (int su = 0; su < 4; ++su) {
          a1[jt][su] = __builtin_amdgcn_mfma_f32_16x16x32_bf16(ah[jt], bh[su], a1[jt][su], 0, 0, 0);
          a1[jt][su] = __builtin_amdgcn_mfma_f32_16x16x32_bf16(al[jt], bh[su], a1[jt][su], 0, 0, 0);
          a1[jt][su] = __builtin_amdgcn_mfma_f32_16x16x32_bf16(ah[jt], bl[su], a1[jt][su], 0, 0, 0);
        }
    }
  }

  // ---- epilogue1: bias, zero col j=0, stats ----
  {
    double ss = 0.0, sq = 0.0;
#pragma unroll
    for (int su = 0; su < 4; ++su) {
      const float bv = b1[(wo * 4 + su) * 16 + col];
#pragma unroll
      for (int jt = 0; jt < 2; ++jt)
#pragma unroll
        for (int r = 0; r < 4; ++r) {
          const int j = jbase + jt * 16 + grp * 4 + r;
          const float val = (j > 0) ? a1[jt][su][r] + bv : 0.f;
          a1[jt][su][r] = val;
          ss += (double)val;
          sq += (double)val * (double)val;
        }
    }
    blockStats(ss, sq, 256.0 * 128.0);
  }
  const float mean1 = bc[0], inv1 = bc[1];

  // ---------------- conv2 stage: all 256 ch from registers (swizzled) -----
#pragma unroll
  for (int su = 0; su < 4; ++su) {
    const int c = (wo * 4 + su) * 16 + col;
#pragma unroll
    for (int jt = 0; jt < 2; ++jt)
#pragma unroll
      for (int r = 0; r < 4; ++r) {
        const int j = jbase + jt * 16 + grp * 4 + r;
        float v = (a1[jt][su][r] - mean1) * inv1;
        v = fmaxf(v, 0.01f * v);
        short h, l;
        split2(v, h, l);
        const int si = SWZ(j, j * CINP + c);
        sH[si] = h;
        sL[si] = l;
      }
  }
  __syncthreads();

  // ---------------- conv2 compute: COUT 128, SUB=2 ----------------
  f32x4 a2[2][2];
#pragma unroll
  for (int jt = 0; jt < 2; ++jt)
#pragma unroll
    for (int su = 0; su < 2; ++su) {
      a2[jt][su][0] = 0.f; a2[jt][su][1] = 0.f;
      a2[jt][su][2] = 0.f; a2[jt][su][3] = 0.f;
    }

#pragma unroll
  for (int kk = 0; kk < 3; ++kk) {
#pragma unroll
    for (int ks = 0; ks < 8; ++ks) {
      const int gks = kk * 8 + ks;
      short8 ah[2], al[2];
#pragma unroll
      for (int jt = 0; jt < 2; ++jt) {
        const int row = nbr[jt][kk];
        const int ei = SWZ(row, row * CINP + ks * 32 + grp * 8);
        ah[jt] = *reinterpret_cast<const short8*>(&sH[ei]);
        al[jt] = *reinterpret_cast<const short8*>(&sL[ei]);
      }
      short8 bh[2], bl[2];
#pragma unroll
      for (int su = 0; su < 2; ++su) {
        const int wi = ((gks * 4 + wo) * 2 + su) * 64 + lane;
        bh[su] = wp2h[wi];
        bl[su] = wp2l[wi];
      }
#pragma unroll
      for (int jt = 0; jt < 2; ++jt)
#pragma unroll
        for (int su = 0; su < 2; ++su) {
          a2[jt][su] = __builtin_amdgcn_mfma_f32_16x16x32_bf16(ah[jt], bh[su], a2[jt][su], 0, 0, 0);
          a2[jt][su] = __builtin_amdgcn_mfma_f32_16x16x32_bf16(al[jt], bh[su], a2[jt][su], 0, 0, 0);
          a2[jt][su] = __builtin_amdgcn_mfma_f32_16x16x32_bf16(ah[jt], bl[su], a2[jt][su], 0, 0, 0);
        }
    }
  }

  // ---- epilogue2 ----
  {
    double ss = 0.0, sq = 0.0;
#pragma unroll
    for (int su = 0; su < 2; ++su) {
      const float bv = b2[(wo * 2 + su) * 16 + col];
#pragma unroll
      for (int jt = 0; jt < 2; ++jt)
#pragma unroll
        for (int r = 0; r < 4; ++r) {
          const int j = jbase + jt * 16 + grp * 4 + r;
          const float val = (j > 0) ? a2[jt][su][r] + bv : 0.f;
          a2[jt][su][r] = val;
          ss += (double)val;
          sq += (double)val * (double)val;
        }
    }
    blockStats(ss, sq, 128.0 * 128.0);
  }
  const float mean2 = bc[0], inv2 = bc[1];

  // ---------------- conv3 stage: all 128 ch (swizzled) ----------------
#pragma unroll
  for (int su = 0; su < 2; ++su) {
    const int c = (wo * 2 + su) * 16 + col;
#pragma unroll
    for (int jt = 0; jt < 2; ++jt)
#pragma unroll
      for (int r = 0; r < 4; ++r) {
        const int j = jbase + jt * 16 + grp * 4 + r;
        float v = (a2[jt][su][r] - mean2) * inv2;
        v = fmaxf(v, 0.01f * v);
        short h, l;
        split2(v, h, l);
        const int si = SWZ(j, j * CINP + c);
        sH[si] = h;
        sL[si] = l;
      }
  }
  __syncthreads();

  // ---------------- conv3 compute: COUT 64, SUB=1 ----------------
  f32x4 a3[2];
#pragma unroll
  for (int jt = 0; jt < 2; ++jt) {
    a3[jt][0] = 0.f; a3[jt][1] = 0.f; a3[jt][2] = 0.f; a3[jt][3] = 0.f;
  }

#pragma unroll
  for (int kk = 0; kk < 3; ++kk) {
#pragma unroll
    for (int ks = 0; ks < 4; ++ks) {
      const int gks = kk * 4 + ks;
      short8 ah[2], al[2];
#pragma unroll
      for (int jt = 0; jt < 2; ++jt) {
        const int row = nbr[jt][kk];
        const int ei = SWZ(row, row * CINP + ks * 32 + grp * 8);
        ah[jt] = *reinterpret_cast<const short8*>(&sH[ei]);
        al[jt] = *reinterpret_cast<const short8*>(&sL[ei]);
      }
      short8 bh, bl;
      {
        const int wi = (gks * 4 + wo) * 64 + lane;
        bh = wp3h[wi];
        bl = wp3l[wi];
      }
#pragma unroll
      for (int jt = 0; jt < 2; ++jt) {
        a3[jt] = __builtin_amdgcn_mfma_f32_16x16x32_bf16(ah[jt], bh, a3[jt], 0, 0, 0);
        a3[jt] = __builtin_amdgcn_mfma_f32_16x16x32_bf16(al[jt], bh, a3[jt], 0, 0, 0);
        a3[jt] = __builtin_amdgcn_mfma_f32_16x16x32_bf16(ah[jt], bl, a3[jt], 0, 0, 0);
      }
    }
  }

  // ---- epilogue3 + stats ----
  {
    double ss = 0.0, sq = 0.0;
    const float bv = b3[wo * 16 + col];
#pragma unroll
    for (int jt = 0; jt < 2; ++jt)
#pragma unroll
      for (int r = 0; r < 4; ++r) {
        const int j = jbase + jt * 16 + grp * 4 + r;
        const float val = (j > 0) ? a3[jt][r] + bv : 0.f;
        a3[jt][r] = val;
        ss += (double)val;
        sq += (double)val * (double)val;
      }
    blockStats(ss, sq, 64.0 * 128.0);
  }
  const float mean3 = bc[0], inv3 = bc[1];

  // ---- maxpool over this wave's j-range, then cross-wj in LDS ----
  {
    float pm = -3.4e38f;
#pragma unroll
    for (int jt = 0; jt < 2; ++jt)
#pragma unroll
      for (int r = 0; r < 4; ++r)
        pm = fmaxf(pm, (a3[jt][r] - mean3) * inv3);
    pm = fmaxf(pm, __shfl_xor(pm, 16, 64));
    pm = fmaxf(pm, __shfl_xor(pm, 32, 64));
    if (lane < 16) poolw[w][col] = pm;
  }
  __syncthreads();

  // ---- 2-layer MLP (wave 0) ----
  if (w == 0) {
    float hval = 0.f;
    if (lane < 32) {
      float a = fb1[lane];
#pragma unroll 8
      for (int c = 0; c < 64; ++c) {
        const int oq = c >> 4, oc16 = c & 15;
        float p = poolw[oq][oc16];
#pragma unroll
        for (int jw = 1; jw < 4; ++jw) p = fmaxf(p, poolw[jw * 4 + oq][oc16]);
        a = fmaf(p, fw1[lane * 64 + c], a);
      }
      hval = fmaxf(a, 0.f) * fw2[lane];
    }
#pragma unroll
    for (int o = 32; o > 0; o >>= 1) hval += __shfl_down(hval, o, 64);
    if (lane == 0) out[b] = hval + fb2[0];
  }
}

// ---------------------------------------------------------------------------
extern "C" void kernel_launch(void* const* d_in, const int* in_sizes, int n_in,
                              void* d_out, int out_size, void* d_ws, size_t ws_size,
                              hipStream_t stream) {
  const float* feature   = (const float*)d_in[0];
  const void*  indexes   = d_in[1];
  const float* col_embed = (const float*)d_in[2];
  const float* op_embed  = (const float*)d_in[3];
  const float* w1  = (const float*)d_in[4];
  const float* b1  = (const float*)d_in[5];
  const float* w2  = (const float*)d_in[6];
  const float* b2  = (const float*)d_in[7];
  const float* w3  = (const float*)d_in[8];
  const float* b3  = (const float*)d_in[9];
  const float* fw1 = (const float*)d_in[10];
  const float* fb1 = (const float*)d_in[11];
  const float* fw2 = (const float*)d_in[12];
  const float* fb2 = (const float*)d_in[13];
  float* out = (float*)d_out;

  char* ws = (char*)d_ws;
  size_t off = 0;
  auto carve = [&](size_t bytes) -> char* {
    off = (off + 255) & ~(size_t)255;
    char* p = ws + off;
    off += bytes;
    return p;
  };
  int*   idx32    = (int*)carve((size_t)S_IDX * sizeof(int));
  short* w1h      = (short*)carve((size_t)S_P1 * sizeof(short));
  short* w1l      = (short*)carve((size_t)S_P1 * sizeof(short));
  short* w2h      = (short*)carve((size_t)S_P2 * sizeof(short));
  short* w2l      = (short*)carve((size_t)S_P2 * sizeof(short));
  short* w3h      = (short*)carve((size_t)S_P3 * sizeof(short));
  short* w3l      = (short*)carve((size_t)S_P3 * sizeof(short));
  short* collateH = (short*)carve((size_t)B_ * 128 * KPAD1 * sizeof(short));
  short* collateL = (short*)carve((size_t)B_ * 128 * KPAD1 * sizeof(short));
  (void)ws_size; (void)in_sizes; (void)n_in; (void)out_size;

  hipLaunchKernelGGL(prep_embed_kernel, dim3(EMBED_BLOCKS + PREP_BLOCKS), dim3(512), 0, stream,
                     feature, col_embed, op_embed, collateH, collateL,
                     indexes, idx32, w1, w1h, w1l, w2, w2h, w2l, w3, w3h, w3l);
  hipLaunchKernelGGL(fused_kernel, dim3(B_), dim3(1024), 0, stream,
                     collateH, collateL, idx32,
                     w1h, w1l, w2h, w2l, w3h, w3l,
                     b1, b2, b3, fw1, fb1, fw2, fb2, out);
}

// Round 17
// 79.465 us; speedup vs baseline: 1.1629x; 1.1413x over previous
//
#include <hip/hip_runtime.h>
#include <hip/hip_bf16.h>
#include <math.h>

// Problem constants (B, N, D) = (256, 128, 128)
#define B_    256
#define N_    128
#define MAXP  30
#define OTHER_ 35
#define CIN1  131
#define NIDX  381

#define KPAD1 160
#define KPAD2 256
#define KPAD3 128
#define S_IDX (B_ * NIDX)          // 97536
#define S_P1  (15 * 4 * 4 * 512)   // 122880  (gks * NWO4 * SUB4 * 512)
#define S_P2  (24 * 4 * 2 * 512)   // 98304
#define S_P3  (12 * 4 * 1 * 512)   // 24576
#define PREP_TOTAL (S_IDX + S_P1 + S_P2 + S_P3)
#define PREP_BLOCKS ((PREP_TOTAL + 511) / 512)

typedef short short8 __attribute__((ext_vector_type(8)));
typedef float f32x4 __attribute__((ext_vector_type(4)));

// RNE split of f32 into hi/lo bf16 via bit math (prep only)
__device__ inline void split1(float v, short& h, short& l) {
  unsigned u = __float_as_uint(v);
  unsigned hb = (u + 0x7fffu + ((u >> 16) & 1u)) >> 16;
  float fh = __uint_as_float(hb << 16);
  float r = v - fh;
  unsigned u2 = __float_as_uint(r);
  unsigned lb = (u2 + 0x7fffu + ((u2 >> 16) & 1u)) >> 16;
  h = (short)hb;
  l = (short)lb;
}

// RNE split via HW cvt — hot path
__device__ inline void split2(float v, short& h, short& l) {
  __hip_bfloat16 hb = __float2bfloat16(v);
  float fh = __bfloat162float(hb);
  __hip_bfloat16 lb = __float2bfloat16(v - fh);
  __builtin_memcpy(&h, &hb, 2);
  __builtin_memcpy(&l, &lb, 2);
}

// ---------------------------------------------------------------------------
// Weight pack: l -> [gks][g][su][lane][e]; g in [0,NWO). Value w[oc][ch][kk],
// oc=(g*SUB+su)*16+(lane&15), ctot=gks*32+((lane>>4)&3)*8+e,
// kk=ctot/KPAD, ch=ctot%KPAD (0 if ch>=KREAL).
// ---------------------------------------------------------------------------
template <int KREAL, int KPAD, int SUB, int NWO>
__device__ inline void packw(int l, const float* __restrict__ w,
                             short* __restrict__ oh, short* __restrict__ ol) {
  const int e = l & 7;
  const int lane = (l >> 3) & 63;
  const int x = l >> 9;
  const int su = x % SUB;
  const int y = x / SUB;
  const int g = y % NWO;
  const int gks = y / NWO;
  const int oc = (g * SUB + su) * 16 + (lane & 15);
  const int ctot = gks * 32 + ((lane >> 4) & 3) * 8 + e;
  const int kk = ctot / KPAD;
  const int ch = ctot - kk * KPAD;
  const float v = (ch < KREAL) ? w[(oc * KREAL + ch) * 3 + kk] : 0.f;
  short h, lo;
  split1(v, h, lo);
  oh[l] = h;
  ol[l] = lo;
}

// ---------------------------------------------------------------------------
// Prep: idx convert (wave-uniform int64 detection) + weight packing only.
// ---------------------------------------------------------------------------
__global__ __launch_bounds__(512) void prep_kernel(
    const void* __restrict__ rawIdx, int* __restrict__ idx32,
    const float* __restrict__ w1, short* __restrict__ w1h, short* __restrict__ w1l,
    const float* __restrict__ w2, short* __restrict__ w2h, short* __restrict__ w2l,
    const float* __restrict__ w3, short* __restrict__ w3h, short* __restrict__ w3l) {
  const int gid = blockIdx.x * 512 + threadIdx.x;
  if (gid < S_IDX) {
    // int64 LE view is (v,0,v,0,...) with v in [0,128)
    const int* r32 = (const int*)rawIdx;
    const int lane = threadIdx.x & 63;
    const int lo = r32[2 * lane];
    const int hi = r32[2 * lane + 1];
    const bool ok = (hi == 0 && lo >= 0 && lo < N_);
    const bool is64 = __all(ok);
    idx32[gid] = is64 ? (int)((const long long*)rawIdx)[gid] : ((const int*)rawIdx)[gid];
  } else if (gid < S_IDX + S_P1) {
    packw<131, KPAD1, 4, 4>(gid - S_IDX, w1, w1h, w1l);
  } else if (gid < S_IDX + S_P1 + S_P2) {
    packw<256, KPAD2, 2, 4>(gid - (S_IDX + S_P1), w2, w2h, w2l);
  } else if (gid < PREP_TOTAL) {
    packw<128, KPAD3, 1, 4>(gid - (S_IDX + S_P1 + S_P2), w3, w3h, w3l);
  }
}

// ---------------------------------------------------------------------------
// FUSED v6 = r14 structure + EMBED PHASE IN-KERNEL (no collate round-trip).
// Block = one batch, 1024 threads = 16 waves (wj 0..3 x wo 0..3).
// Phase E: stage feature[b] (128x133 f32) + tables into the (later) sH/sL
// LDS region; compute collate fragments into registers; barrier; write
// split-bf16 collate straight into sH/sL rows (feat region dead).
// Then conv1/conv2/conv3 + stats + maxpool + MLP exactly as r14.
// Only global write: out[b].
// ---------------------------------------------------------------------------
__global__ __launch_bounds__(1024, 1) void fused_kernel(
    const float* __restrict__ feature,
    const float* __restrict__ col_embed,   // (200,32)
    const float* __restrict__ op_embed,    // (20,32)
    const int* __restrict__ idx,
    const short* __restrict__ w1h, const short* __restrict__ w1l,
    const short* __restrict__ w2h, const short* __restrict__ w2l,
    const short* __restrict__ w3h, const short* __restrict__ w3l,
    const float* __restrict__ b1, const float* __restrict__ b2,
    const float* __restrict__ b3,
    const float* __restrict__ fw1, const float* __restrict__ fb1,
    const float* __restrict__ fw2, const float* __restrict__ fb2,
    float* __restrict__ out) {
  constexpr int CINP = 264;   // shorts per row (528 B)

  __shared__ short smem[128 * CINP * 2];   // sH | sL, 135.2 KB
  __shared__ int nb_s[NIDX];
  __shared__ double red[32];
  __shared__ float bc[2];
  __shared__ float poolw[16][16];

  short* sH = smem;
  short* sL = smem + 128 * CINP;
  float* feat = (float*)smem;                 // [128][133], 68.1 KB (aliased)
  float* ceL  = ((float*)smem) + 128 * 133;   // 200x32, aliased
  float* oeL  = ceL + 200 * 32;               // 20x32

  const int b = blockIdx.x;
  const int tid = threadIdx.x;
  const int lane = tid & 63;
  const int w = tid >> 6;       // 0..15
  const int wj = w >> 2;        // 0..3
  const int wo = w & 3;         // 0..3
  const int col = lane & 15;
  const int grp = (lane >> 4) & 3;
  const int jbase = wj * 32;
  const int cl = lane & 31;

  const short8* __restrict__ wp1h = (const short8*)w1h;
  const short8* __restrict__ wp1l = (const short8*)w1l;
  const short8* __restrict__ wp2h = (const short8*)w2h;
  const short8* __restrict__ wp2l = (const short8*)w2l;
  const short8* __restrict__ wp3h = (const short8*)w3h;
  const short8* __restrict__ wp3l = (const short8*)w3l;

  auto blockStats = [&](double ss, double sq, double cnt) {
#pragma unroll
    for (int o = 32; o > 0; o >>= 1) {
      ss += __shfl_down(ss, o, 64);
      sq += __shfl_down(sq, o, 64);
    }
    if (lane == 0) { red[w * 2] = ss; red[w * 2 + 1] = sq; }
    __syncthreads();
    if (tid == 0) {
      double S = 0.0, Q = 0.0;
#pragma unroll
      for (int i = 0; i < 16; ++i) { S += red[i * 2]; Q += red[i * 2 + 1]; }
      const double m = S / cnt;
      double var = (Q - S * S / cnt) / (cnt - 1.0);
      if (var < 0.0) var = 0.0;
      bc[0] = (float)m;
      bc[1] = (float)(1.0 / (sqrt(var) + 1e-5));
    }
    __syncthreads();
  };

  // ================= PHASE E: embed =================
  // E1: stage feature[b] (d-major 128x128 -> feat[d][n], stride 133) +
  //     both tables + idx.
  {
    const float* fb = feature + (size_t)b * 16384;
#pragma unroll
    for (int it = 0; it < 4; ++it) {
      const int t = it * 1024 + tid;
      const int d = t >> 5;
      const int c4 = (t & 31) * 4;
      const float4 v = *reinterpret_cast<const float4*>(&fb[d * 128 + c4]);
      float* p = &feat[d * 133 + c4];
      p[0] = v.x; p[1] = v.y; p[2] = v.z; p[3] = v.w;
    }
    // tables (float4 aligned: base offsets are multiples of 4 floats)
    const float4* s = (const float4*)col_embed;
    float4* d4 = (float4*)ceL;
#pragma unroll
    for (int it = 0; it < 2; ++it) {
      const int t = it * 1024 + tid;
      if (t < 1600) d4[t] = s[t];
    }
    if (tid < 160) ((float4*)oeL)[tid] = ((const float4*)op_embed)[tid];
    if (tid < NIDX) nb_s[tid] = idx[b * NIDX + tid];
  }
  __syncthreads();

  // E2: per wave 8 nodes -> collate fragments in registers
  float emb[8], oth[8], par[8];
#pragma unroll
  for (int ni = 0; ni < 8; ++ni) {
    const int n = w * 8 + ni;
    int civ = 0, oiv = 0;
    if (lane < MAXP) civ = (int)feat[(OTHER_ + lane) * 133 + n];
    if (lane >= 32 && lane < 32 + MAXP) oiv = (int)feat[(OTHER_ + MAXP + (lane - 32)) * 133 + n];
    const int L = (int)feat[95 * 133 + n];
    float acc = 0.f;
    for (int i = 0; i < L; ++i) {
      const int cv = __shfl(civ, i);
      const int ov = __shfl(oiv, 32 + i);
      acc += (lane < 32) ? ceL[cv * 32 + cl] : oeL[ov * 32 + cl];
    }
    emb[ni] = acc;
    oth[ni] = (lane < 35) ? feat[lane * 133 + n] : 0.f;
    par[ni] = (lane < 32) ? feat[(96 + lane) * 133 + n] : 0.f;
  }
  // nbr while feat still live (nb_s separate, but compute now anyway)
  int nbr[2][3];
#pragma unroll
  for (int jt = 0; jt < 2; ++jt) {
    const int jA = jbase + jt * 16 + col;
#pragma unroll
    for (int kk = 0; kk < 3; ++kk)
      nbr[jt][kk] = (jA > 0) ? nb_s[(jA - 1) * 3 + kk] : 0;
  }
  __syncthreads();   // all feat/table reads done; region reusable

  // E3: write collate (split bf16) into sH/sL rows
#pragma unroll
  for (int ni = 0; ni < 8; ++ni) {
    const int n = w * 8 + ni;
    const int base = n * CINP;
    short h, l;
    split2(emb[ni], h, l);
    sH[base + 35 + lane] = h; sL[base + 35 + lane] = l;
    if (lane < 35) {
      split2(oth[ni], h, l);
      sH[base + lane] = h; sL[base + lane] = l;
    }
    if (lane < 32) {
      split2(par[ni], h, l);
      sH[base + 99 + lane] = h; sL[base + 99 + lane] = l;
    }
    if (lane < 29) { sH[base + 131 + lane] = 0; sL[base + 131 + lane] = 0; }
  }
  __syncthreads();

  // ================= conv1: COUT 256, SUB=4 =================
  f32x4 a1[2][4];
#pragma unroll
  for (int jt = 0; jt < 2; ++jt)
#pragma unroll
    for (int su = 0; su < 4; ++su) {
      a1[jt][su][0] = 0.f; a1[jt][su][1] = 0.f;
      a1[jt][su][2] = 0.f; a1[jt][su][3] = 0.f;
    }

#pragma unroll
  for (int kk = 0; kk < 3; ++kk) {
#pragma unroll
    for (int ks = 0; ks < 5; ++ks) {
      const int gks = kk * 5 + ks;
      short8 ah[2], al[2];
#pragma unroll
      for (int jt = 0; jt < 2; ++jt) {
        const int ei = nbr[jt][kk] * CINP + ks * 32 + grp * 8;
        ah[jt] = *reinterpret_cast<const short8*>(&sH[ei]);
        al[jt] = *reinterpret_cast<const short8*>(&sL[ei]);
      }
      short8 bh[4], bl[4];
#pragma unroll
      for (int su = 0; su < 4; ++su) {
        const int wi = ((gks * 4 + wo) * 4 + su) * 64 + lane;
        bh[su] = wp1h[wi];
        bl[su] = wp1l[wi];
      }
#pragma unroll
      for (int jt = 0; jt < 2; ++jt)
#pragma unroll
        for (int su = 0; su < 4; ++su) {
          a1[jt][su] = __builtin_amdgcn_mfma_f32_16x16x32_bf16(ah[jt], bh[su], a1[jt][su], 0, 0, 0);
          a1[jt][su] = __builtin_amdgcn_mfma_f32_16x16x32_bf16(al[jt], bh[su], a1[jt][su], 0, 0, 0);
          a1[jt][su] = __builtin_amdgcn_mfma_f32_16x16x32_bf16(ah[jt], bl[su], a1[jt][su], 0, 0, 0);
        }
    }
  }

  // ---- epilogue1: bias, zero col j=0, stats ----
  {
    double ss = 0.0, sq = 0.0;
#pragma unroll
    for (int su = 0; su < 4; ++su) {
      const float bv = b1[(wo * 4 + su) * 16 + col];
#pragma unroll
      for (int jt = 0; jt < 2; ++jt)
#pragma unroll
        for (int r = 0; r < 4; ++r) {
          const int j = jbase + jt * 16 + grp * 4 + r;
          const float val = (j > 0) ? a1[jt][su][r] + bv : 0.f;
          a1[jt][su][r] = val;
          ss += (double)val;
          sq += (double)val * (double)val;
        }
    }
    blockStats(ss, sq, 256.0 * 128.0);
  }
  const float mean1 = bc[0], inv1 = bc[1];

  // ---- conv2 stage: all 256 ch from registers ----
#pragma unroll
  for (int su = 0; su < 4; ++su) {
    const int c = (wo * 4 + su) * 16 + col;
#pragma unroll
    for (int jt = 0; jt < 2; ++jt)
#pragma unroll
      for (int r = 0; r < 4; ++r) {
        const int j = jbase + jt * 16 + grp * 4 + r;
        float v = (a1[jt][su][r] - mean1) * inv1;
        v = fmaxf(v, 0.01f * v);
        short h, l;
        split2(v, h, l);
        sH[j * CINP + c] = h;
        sL[j * CINP + c] = l;
      }
  }
  __syncthreads();

  // ================= conv2: COUT 128, SUB=2 =================
  f32x4 a2[2][2];
#pragma unroll
  for (int jt = 0; jt < 2; ++jt)
#pragma unroll
    for (int su = 0; su < 2; ++su) {
      a2[jt][su][0] = 0.f; a2[jt][su][1] = 0.f;
      a2[jt][su][2] = 0.f; a2[jt][su][3] = 0.f;
    }

#pragma unroll
  for (int kk = 0; kk < 3; ++kk) {
#pragma unroll
    for (int ks = 0; ks < 8; ++ks) {
      const int gks = kk * 8 + ks;
      short8 ah[2], al[2];
#pragma unroll
      for (int jt = 0; jt < 2; ++jt) {
        const int ei = nbr[jt][kk] * CINP + ks * 32 + grp * 8;
        ah[jt] = *reinterpret_cast<const short8*>(&sH[ei]);
        al[jt] = *reinterpret_cast<const short8*>(&sL[ei]);
      }
      short8 bh[2], bl[2];
#pragma unroll
      for (int su = 0; su < 2; ++su) {
        const int wi = ((gks * 4 + wo) * 2 + su) * 64 + lane;
        bh[su] = wp2h[wi];
        bl[su] = wp2l[wi];
      }
#pragma unroll
      for (int jt = 0; jt < 2; ++jt)
#pragma unroll
        for (int su = 0; su < 2; ++su) {
          a2[jt][su] = __builtin_amdgcn_mfma_f32_16x16x32_bf16(ah[jt], bh[su], a2[jt][su], 0, 0, 0);
          a2[jt][su] = __builtin_amdgcn_mfma_f32_16x16x32_bf16(al[jt], bh[su], a2[jt][su], 0, 0, 0);
          a2[jt][su] = __builtin_amdgcn_mfma_f32_16x16x32_bf16(ah[jt], bl[su], a2[jt][su], 0, 0, 0);
        }
    }
  }

  // ---- epilogue2 ----
  {
    double ss = 0.0, sq = 0.0;
#pragma unroll
    for (int su = 0; su < 2; ++su) {
      const float bv = b2[(wo * 2 + su) * 16 + col];
#pragma unroll
      for (int jt = 0; jt < 2; ++jt)
#pragma unroll
        for (int r = 0; r < 4; ++r) {
          const int j = jbase + jt * 16 + grp * 4 + r;
          const float val = (j > 0) ? a2[jt][su][r] + bv : 0.f;
          a2[jt][su][r] = val;
          ss += (double)val;
          sq += (double)val * (double)val;
        }
    }
    blockStats(ss, sq, 128.0 * 128.0);
  }
  const float mean2 = bc[0], inv2 = bc[1];

  // ---- conv3 stage: all 128 ch ----
#pragma unroll
  for (int su = 0; su < 2; ++su) {
    const int c = (wo * 2 + su) * 16 + col;
#pragma unroll
    for (int jt = 0; jt < 2; ++jt)
#pragma unroll
      for (int r = 0; r < 4; ++r) {
        const int j = jbase + jt * 16 + grp * 4 + r;
        float v = (a2[jt][su][r] - mean2) * inv2;
        v = fmaxf(v, 0.01f * v);
        short h, l;
        split2(v, h, l);
        sH[j * CINP + c] = h;
        sL[j * CINP + c] = l;
      }
  }
  __syncthreads();

  // ================= conv3: COUT 64, SUB=1 =================
  f32x4 a3[2];
#pragma unroll
  for (int jt = 0; jt < 2; ++jt) {
    a3[jt][0] = 0.f; a3[jt][1] = 0.f; a3[jt][2] = 0.f; a3[jt][3] = 0.f;
  }

#pragma unroll
  for (int kk = 0; kk < 3; ++kk) {
#pragma unroll
    for (int ks = 0; ks < 4; ++ks) {
      const int gks = kk * 4 + ks;
      short8 ah[2], al[2];
#pragma unroll
      for (int jt = 0; jt < 2; ++jt) {
        const int ei = nbr[jt][kk] * CINP + ks * 32 + grp * 8;
        ah[jt] = *reinterpret_cast<const short8*>(&sH[ei]);
        al[jt] = *reinterpret_cast<const short8*>(&sL[ei]);
      }
      short8 bh, bl;
      {
        const int wi = (gks * 4 + wo) * 64 + lane;
        bh = wp3h[wi];
        bl = wp3l[wi];
      }
#pragma unroll
      for (int jt = 0; jt < 2; ++jt) {
        a3[jt] = __builtin_amdgcn_mfma_f32_16x16x32_bf16(ah[jt], bh, a3[jt], 0, 0, 0);
        a3[jt] = __builtin_amdgcn_mfma_f32_16x16x32_bf16(al[jt], bh, a3[jt], 0, 0, 0);
        a3[jt] = __builtin_amdgcn_mfma_f32_16x16x32_bf16(ah[jt], bl, a3[jt], 0, 0, 0);
      }
    }
  }

  // ---- epilogue3 + stats ----
  {
    double ss = 0.0, sq = 0.0;
    const float bv = b3[wo * 16 + col];
#pragma unroll
    for (int jt = 0; jt < 2; ++jt)
#pragma unroll
      for (int r = 0; r < 4; ++r) {
        const int j = jbase + jt * 16 + grp * 4 + r;
        const float val = (j > 0) ? a3[jt][r] + bv : 0.f;
        a3[jt][r] = val;
        ss += (double)val;
        sq += (double)val * (double)val;
      }
    blockStats(ss, sq, 64.0 * 128.0);
  }
  const float mean3 = bc[0], inv3 = bc[1];

  // ---- maxpool over this wave's j-range, then cross-wj in LDS ----
  {
    float pm = -3.4e38f;
#pragma unroll
    for (int jt = 0; jt < 2; ++jt)
#pragma unroll
      for (int r = 0; r < 4; ++r)
        pm = fmaxf(pm, (a3[jt][r] - mean3) * inv3);
    pm = fmaxf(pm, __shfl_xor(pm, 16, 64));
    pm = fmaxf(pm, __shfl_xor(pm, 32, 64));
    if (lane < 16) poolw[w][col] = pm;
  }
  __syncthreads();

  // ---- 2-layer MLP (wave 0) ----
  if (w == 0) {
    float hval = 0.f;
    if (lane < 32) {
      float a = fb1[lane];
#pragma unroll 8
      for (int c = 0; c < 64; ++c) {
        const int oq = c >> 4, oc16 = c & 15;
        float p = poolw[oq][oc16];
#pragma unroll
        for (int jw = 1; jw < 4; ++jw) p = fmaxf(p, poolw[jw * 4 + oq][oc16]);
        a = fmaf(p, fw1[lane * 64 + c], a);
      }
      hval = fmaxf(a, 0.f) * fw2[lane];
    }
#pragma unroll
    for (int o = 32; o > 0; o >>= 1) hval += __shfl_down(hval, o, 64);
    if (lane == 0) out[b] = hval + fb2[0];
  }
}

// ---------------------------------------------------------------------------
extern "C" void kernel_launch(void* const* d_in, const int* in_sizes, int n_in,
                              void* d_out, int out_size, void* d_ws, size_t ws_size,
                              hipStream_t stream) {
  const float* feature   = (const float*)d_in[0];
  const void*  indexes   = d_in[1];
  const float* col_embed = (const float*)d_in[2];
  const float* op_embed  = (const float*)d_in[3];
  const float* w1  = (const float*)d_in[4];
  const float* b1  = (const float*)d_in[5];
  const float* w2  = (const float*)d_in[6];
  const float* b2  = (const float*)d_in[7];
  const float* w3  = (const float*)d_in[8];
  const float* b3  = (const float*)d_in[9];
  const float* fw1 = (const float*)d_in[10];
  const float* fb1 = (const float*)d_in[11];
  const float* fw2 = (const float*)d_in[12];
  const float* fb2 = (const float*)d_in[13];
  float* out = (float*)d_out;

  char* ws = (char*)d_ws;
  size_t off = 0;
  auto carve = [&](size_t bytes) -> char* {
    off = (off + 255) & ~(size_t)255;
    char* p = ws + off;
    off += bytes;
    return p;
  };
  int*   idx32 = (int*)carve((size_t)S_IDX * sizeof(int));
  short* w1h   = (short*)carve((size_t)S_P1 * sizeof(short));
  short* w1l   = (short*)carve((size_t)S_P1 * sizeof(short));
  short* w2h   = (short*)carve((size_t)S_P2 * sizeof(short));
  short* w2l   = (short*)carve((size_t)S_P2 * sizeof(short));
  short* w3h   = (short*)carve((size_t)S_P3 * sizeof(short));
  short* w3l   = (short*)carve((size_t)S_P3 * sizeof(short));
  (void)ws_size; (void)in_sizes; (void)n_in; (void)out_size;

  hipLaunchKernelGGL(prep_kernel, dim3(PREP_BLOCKS), dim3(512), 0, stream,
                     indexes, idx32, w1, w1h, w1l, w2, w2h, w2l, w3, w3h, w3l);
  hipLaunchKernelGGL(fused_kernel, dim3(B_), dim3(1024), 0, stream,
                     feature, col_embed, op_embed, idx32,
                     w1h, w1l, w2h, w2l, w3h, w3l,
                     b1, b2, b3, fw1, fb1, fw2, fb2, out);
}